// Round 8
// baseline (785.917 us; speedup 1.0000x reference)
//
#include <hip/hip_runtime.h>

#define TAGS 128
#define SEQ 1024
#define BATCH 128
#define LOG16 2.7725887222397812f

typedef __attribute__((ext_vector_type(8))) _Float16 half8;
typedef __attribute__((ext_vector_type(2))) _Float16 half2v;
typedef __attribute__((ext_vector_type(16))) float float16;

#define GS_BYTES ((size_t)4 * SEQ * 64 * 32 * 4)   // 33.5 MB of u32 (f16 pairs)

static __device__ __forceinline__ unsigned pk2u(float a, float b) {
    return __builtin_bit_cast(unsigned, __builtin_amdgcn_cvt_pkrtz(a, b));
}

// ---------------------------------------------------------------------------
// Pass 1: Gs = f16x2 of exp(yp)/16 (2^-4 headroom folded in; exact exponent
// shift, accounted as +log16/step in C). Layout (validated r4-7): pair
// p=(t*4+s)*2+qq at lane (hi,n) holds u=32t+8s+4hi+2qq+{0,1}, b=32grp+n.
// LDS transpose for coalesced reads (r7).
// ---------------------------------------------------------------------------
#define EPITCH 66
__global__ __launch_bounds__(64, 1)
void exp_pack(const float* __restrict__ yp, unsigned* __restrict__ gs)
{
    __shared__ unsigned ldsT[32 * EPITCH];
    const int blk = blockIdx.x;               // grp*SEQ + i
    const int grp = blk >> 10, i = blk & (SEQ - 1);
    const int tid = threadIdx.x;
    const float* src = yp + (size_t)(grp * 32) * SEQ * TAGS + (size_t)i * TAGS;

#pragma unroll
    for (int k = 0; k < 16; ++k) {
        int f = tid + 64 * k;
        int r = f >> 5, c = f & 31;
        const float4 v = *(const float4*)(src + (size_t)r * SEQ * TAGS + 4 * c);
        uint2 d;
        d.x = pk2u(__expf(v.x) * 0.0625f, __expf(v.y) * 0.0625f);
        d.y = pk2u(__expf(v.z) * 0.0625f, __expf(v.w) * 0.0625f);
        *(uint2*)&ldsT[r * EPITCH + 2 * c] = d;
    }
    __syncthreads();

    const int hi = tid >> 5, n = tid & 31;
    unsigned* dst = gs + ((size_t)blk * 64 + tid) * 32;
    uint2 w[16];
#pragma unroll
    for (int t = 0; t < 4; ++t)
#pragma unroll
        for (int s = 0; s < 4; ++s) {
            int pi = 16 * t + 4 * s + 2 * hi;
            w[t * 4 + s] = *(const uint2*)&ldsT[n * EPITCH + pi];
        }
#pragma unroll
    for (int q = 0; q < 8; ++q)
        ((uint4*)dst)[q] = make_uint4(w[2 * q].x, w[2 * q].y,
                                      w[2 * q + 1].x, w[2 * q + 1].y);
}

// ---------------------------------------------------------------------------
// State pks[32]: dword (ks*4+dw) = f16x2 of rows u=32t+8s+4hi+{2qq,2qq+1},
// ks=2t+(s>>1), dw=2(s&1)+qq. pks[4ks..4ks+3] IS the B-frag for K-slice ks.
// ---------------------------------------------------------------------------
__device__ __forceinline__ void load_g(uint4 (&gq)[8], const unsigned* gs,
                                       int grp, int idx, int lane)
{
    const uint4* p = (const uint4*)(gs + ((size_t)(grp * SEQ + idx) * 64 + lane) * 32);
#pragma unroll
    for (int k = 0; k < 8; ++k) gq[k] = p[k];
}

__device__ __forceinline__ void mfma_all(const half8 (&af)[4][8],
                                         const unsigned (&pks)[32],
                                         float16 (&acc)[4])
{
    float16 z;
#pragma unroll
    for (int e = 0; e < 16; ++e) z[e] = 0.f;
#pragma unroll
    for (int ks = 0; ks < 8; ++ks) {
        uint4 bq = {pks[4 * ks], pks[4 * ks + 1], pks[4 * ks + 2], pks[4 * ks + 3]};
        half8 bf = __builtin_bit_cast(half8, bq);
#pragma unroll
        for (int T = 0; T < 4; ++T)
            acc[T] = __builtin_amdgcn_mfma_f32_32x32x16_f16(
                af[T][ks], bf, ks == 0 ? z : acc[T], 0, 0, 0);
    }
}

// new_state = (f16(acc) .* G) * rn ;  C += log(q0) + log16   (q0 precomputed)
__device__ __forceinline__ void epi(const float16 (&acc)[4], const uint4 (&gq)[8],
                                    float q0, unsigned (&pks)[32], float& C)
{
    float rn = __builtin_amdgcn_rcpf(q0);
    C += __logf(q0) + LOG16;
    half2v rnh = __builtin_bit_cast(half2v, pk2u(rn, rn));
    const unsigned* gu = (const unsigned*)gq;
#pragma unroll
    for (int t = 0; t < 4; ++t)
#pragma unroll
        for (int s = 0; s < 4; ++s)
#pragma unroll
            for (int qq = 0; qq < 2; ++qq) {
                int e = 4 * s + 2 * qq;
                half2v hv = __builtin_bit_cast(half2v, pk2u(acc[t][e], acc[t][e + 1]));
                half2v g2 = __builtin_bit_cast(half2v, gu[(t * 4 + s) * 2 + qq]);
                hv = hv * g2 * rnh;
                pks[(2 * t + (s >> 1)) * 4 + 2 * (s & 1) + qq] =
                    __builtin_bit_cast(unsigned, hv);
            }
}

// ---------------------------------------------------------------------------
// Main kernel: 4 blocks x 1 wave; each wave runs TWO same-direction chains
// interleaved (A,B) so ladderB/epiA hide ladderA/shflB latencies.
// Blocks 0-1: fwd grps {0,1},{2,3} -> F_512; blocks 2-3: bwd -> V=E.W_513.
// Z = F_512 . V per batch col.
// ---------------------------------------------------------------------------
__global__ __launch_bounds__(64, 1)
void crf_seq(const unsigned* __restrict__ gs, const float* __restrict__ Ain,
             float* __restrict__ Fst, float* __restrict__ Vst,
             float* __restrict__ Cf, float* __restrict__ Cb)
{
    const int blk = blockIdx.x;
    const bool fwd = blk < 2;
    const int pr = blk & 1;
    const int grpA = 2 * pr, grpB = 2 * pr + 1;
    const int lane = threadIdx.x;
    const int hi = lane >> 5, l31 = lane & 31;

    // sigma-permuted E A-frags: slot j of frag (T,ks) = E_eff[sig(ks,hi,j)][32T+l31]
    half8 af[4][8];
#pragma unroll
    for (int T = 0; T < 4; ++T)
#pragma unroll
        for (int ks = 0; ks < 8; ++ks) {
            unsigned q[4];
#pragma unroll
            for (int jj = 0; jj < 4; ++jj) {
                int u0 = 32 * (ks >> 1) + 8 * (2 * (ks & 1) + (jj >> 1))
                       + 4 * hi + 2 * (jj & 1);
                int m = 32 * T + l31;
                float e0, e1;
                if (fwd) { e0 = __expf(Ain[u0 * TAGS + m]);
                           e1 = __expf(Ain[(u0 + 1) * TAGS + m]); }
                else     { e0 = __expf(Ain[m * TAGS + u0]);
                           e1 = __expf(Ain[m * TAGS + u0 + 1]); }
                q[jj] = pk2u(e0, e1);
            }
            uint4 qv = {q[0], q[1], q[2], q[3]};
            af[T][ks] = __builtin_bit_cast(half8, qv);
        }

    // init state p_hat = G(start); C = log16 accounts the /16 in G-hat
    unsigned pksA[32], pksB[32];
    {
        const int st = fwd ? 0 : SEQ - 1;
        const unsigned* gA = gs + ((size_t)(grpA * SEQ + st) * 64 + lane) * 32;
        const unsigned* gB = gs + ((size_t)(grpB * SEQ + st) * 64 + lane) * 32;
#pragma unroll
        for (int t = 0; t < 4; ++t)
#pragma unroll
            for (int s = 0; s < 4; ++s)
#pragma unroll
                for (int qq = 0; qq < 2; ++qq) {
                    int dst = (2 * t + (s >> 1)) * 4 + 2 * (s & 1) + qq;
                    int srcp = (t * 4 + s) * 2 + qq;
                    pksA[dst] = gA[srcp];
                    pksB[dst] = gB[srcp];
                }
    }
    float CA = LOG16, CB = LOG16;
    float16 accA[4], accB[4];
    uint4 gqA[8], gqB[8];
    load_g(gqA, gs, grpA, fwd ? 1 : 1022, lane);
    load_g(gqB, gs, grpB, fwd ? 1 : 1022, lane);

#pragma unroll 1
    for (int j = 1; j <= 510; ++j) {
        mfma_all(af, pksA, accA);
        float vA = accA[0][0];
        float vAp = __shfl_xor(vA, 32, 64);          // latency hidden by ladderB
        mfma_all(af, pksB, accB);
        float vB = accB[0][0];
        float vBp = __shfl_xor(vB, 32, 64);          // latency hidden by epiA
        int nxt = fwd ? j + 1 : 1022 - j;
        epi(accA, gqA, hi ? vAp : vA, pksA, CA);
        load_g(gqA, gs, grpA, nxt, lane);
        epi(accB, gqB, hi ? vBp : vB, pksB, CB);
        load_g(gqB, gs, grpB, nxt, lane);
    }

    if (fwd) {
        // step 511 (gq = G_511), then bare ladder + F-write with G_512
        mfma_all(af, pksA, accA);
        float vA = accA[0][0]; float vAp = __shfl_xor(vA, 32, 64);
        mfma_all(af, pksB, accB);
        float vB = accB[0][0]; float vBp = __shfl_xor(vB, 32, 64);
        epi(accA, gqA, hi ? vAp : vA, pksA, CA);
        load_g(gqA, gs, grpA, 512, lane);
        epi(accB, gqB, hi ? vBp : vB, pksB, CB);
        load_g(gqB, gs, grpB, 512, lane);
        mfma_all(af, pksA, accA);
        mfma_all(af, pksB, accB);
#pragma unroll
        for (int ch = 0; ch < 2; ++ch) {
            const float16* acc = ch ? accB : accA;
            const uint4* gq = ch ? gqB : gqA;
            float C = ch ? CB : CA;
            int grp = ch ? grpB : grpA;
            float v0 = acc[0][0];
            float vp = __shfl_xor(v0, 32, 64);
            float q0 = hi ? vp : v0;
            float rn = __builtin_amdgcn_rcpf(q0);
            C += __logf(q0) + LOG16;                 // G_512 is g/16
            const unsigned* gu = (const unsigned*)gq;
            int b = grp * 32 + l31;
#pragma unroll
            for (int t = 0; t < 4; ++t)
#pragma unroll
                for (int s = 0; s < 4; ++s)
#pragma unroll
                    for (int qq = 0; qq < 2; ++qq) {
                        half2v g2 = __builtin_bit_cast(half2v, gu[(t * 4 + s) * 2 + qq]);
                        int e = 4 * s + 2 * qq;
                        int u = 32 * t + 8 * s + 4 * hi + 2 * qq;
                        Fst[(size_t)b * TAGS + u]     = acc[t][e] * rn * (float)g2[0];
                        Fst[(size_t)b * TAGS + u + 1] = acc[t][e + 1] * rn * (float)g2[1];
                    }
            if (hi == 0) Cf[b] = C;
        }
    } else {
        mfma_all(af, pksA, accA);
        mfma_all(af, pksB, accB);
#pragma unroll
        for (int ch = 0; ch < 2; ++ch) {
            const float16* acc = ch ? accB : accA;
            float C = ch ? CB : CA;
            int grp = ch ? grpB : grpA;
            float v0 = acc[0][0];
            float vp = __shfl_xor(v0, 32, 64);
            float q0 = hi ? vp : v0;
            float rn = __builtin_amdgcn_rcpf(q0);
            C += __logf(q0);
            int b = grp * 32 + l31;
#pragma unroll
            for (int t = 0; t < 4; ++t)
#pragma unroll
                for (int r = 0; r < 16; ++r) {
                    int u = 32 * t + (r & 3) + 8 * (r >> 2) + 4 * hi;
                    Vst[(size_t)b * TAGS + u] = acc[t][r] * rn;
                }
            if (hi == 0) Cb[b] = C;
        }
    }
}

// logZ_b = Cf + Cb + log(F_512 . V);  out += logZ_b / BATCH
__global__ __launch_bounds__(128, 1)
void crf_combine(const float* __restrict__ Fst, const float* __restrict__ Vst,
                 const float* __restrict__ Cf, const float* __restrict__ Cb,
                 float* __restrict__ out)
{
    int b = threadIdx.x;
    const float* f = Fst + (size_t)b * TAGS;
    const float* v = Vst + (size_t)b * TAGS;
    float s = 0.f;
#pragma unroll
    for (int u = 0; u < TAGS; ++u) s += f[u] * v[u];
    float logZ = Cf[b] + Cb[b] + __logf(s);
    atomicAdd(out, logZ * (1.0f / (float)BATCH));
}

// Gold-path score (validated rounds 1-7): adds -score_b / BATCH
__global__ __launch_bounds__(128, 1)
void crf_score(const float* __restrict__ yp, const int* __restrict__ yt,
               const float* __restrict__ mask, const float* __restrict__ A,
               float* __restrict__ out)
{
    const int b = blockIdx.x;
    const int u = threadIdx.x;
    __shared__ float wred[2];

    const float* __restrict__ ypb = yp + (size_t)b * SEQ * TAGS;
    const float* __restrict__ mb  = mask + (size_t)b * SEQ;
    const int*   __restrict__ ytb = yt + (size_t)b * SEQ;

    float sc = 0.f;
#pragma unroll
    for (int k = 0; k < SEQ / TAGS; ++k) {
        int s = u + k * TAGS;
        int l = ytb[s];
        float m = mb[s];
        sc += ypb[s * TAGS + l] * m;
        if (s + 1 < SEQ) {
            int l2 = ytb[s + 1];
            sc += A[l * TAGS + l2] * m * mb[s + 1];
        }
    }
#pragma unroll
    for (int off = 32; off > 0; off >>= 1)
        sc += __shfl_down(sc, off, 64);
    if ((u & 63) == 0) wred[u >> 6] = sc;
    __syncthreads();
    if (u == 0) atomicAdd(out, -(wred[0] + wred[1]) * (1.0f / (float)BATCH));
}

extern "C" void kernel_launch(void* const* d_in, const int* in_sizes, int n_in,
                              void* d_out, int out_size, void* d_ws, size_t ws_size,
                              hipStream_t stream) {
    const float* yp   = (const float*)d_in[0];   // (128,1024,128) f32
    const int*   yt   = (const int*)d_in[1];     // (128,1024) int
    const float* mask = (const float*)d_in[2];   // (128,1024) f32
    const float* A    = (const float*)d_in[3];   // (128,128) f32
    float* out = (float*)d_out;

    unsigned* gs = (unsigned*)d_ws;
    float* Fst = (float*)((char*)d_ws + GS_BYTES);
    float* Vst = Fst + BATCH * TAGS;
    float* Cf  = Vst + BATCH * TAGS;
    float* Cb  = Cf + BATCH;

    (void)hipMemsetAsync(out, 0, sizeof(float), stream);
    crf_score<<<BATCH, TAGS, 0, stream>>>(yp, yt, mask, A, out);
    exp_pack<<<4 * SEQ, 64, 0, stream>>>(yp, gs);
    crf_seq<<<4, 64, 0, stream>>>(gs, A, Fst, Vst, Cf, Cb);
    crf_combine<<<1, BATCH, 0, stream>>>(Fst, Vst, Cf, Cb, out);
}

// Round 10
// 580.476 us; speedup vs baseline: 1.3539x; 1.3539x over previous
//
#include <hip/hip_runtime.h>

#define TAGS 128
#define SEQ 1024
#define BATCH 128
#define LOG16 2.7725887222397812f

typedef __attribute__((ext_vector_type(8))) _Float16 half8;
typedef __attribute__((ext_vector_type(2))) _Float16 half2v;
typedef __attribute__((ext_vector_type(16))) float float16;

#define GS_BYTES ((size_t)4 * SEQ * 64 * 32 * 4)   // 33.5 MB of u32 (f16 pairs)

static __device__ __forceinline__ unsigned pk2u(float a, float b) {
    return __builtin_bit_cast(unsigned, __builtin_amdgcn_cvt_pkrtz(a, b));
}
static __device__ __forceinline__ half8 bfrag(const unsigned (&p)[32], int ks) {
    uint4 q = {p[4 * ks], p[4 * ks + 1], p[4 * ks + 2], p[4 * ks + 3]};
    return __builtin_bit_cast(half8, q);
}
#define MFMA(a, b, c) __builtin_amdgcn_mfma_f32_32x32x16_f16((a), (b), (c), 0, 0, 0)

// ---------------------------------------------------------------------------
// Pass 1 (validated r4-8): Gs = f16x2 of exp(yp)/16, pair p=(t*4+s)*2+qq at
// lane (hi,n) holds u=32t+8s+4hi+2qq+{0,1}, b=32grp+n. LDS-transposed reads.
// ---------------------------------------------------------------------------
#define EPITCH 66
__global__ __launch_bounds__(64, 1)
void exp_pack(const float* __restrict__ yp, unsigned* __restrict__ gs)
{
    __shared__ unsigned ldsT[32 * EPITCH];
    const int blk = blockIdx.x;               // grp*SEQ + i
    const int grp = blk >> 10, i = blk & (SEQ - 1);
    const int tid = threadIdx.x;
    const float* src = yp + (size_t)(grp * 32) * SEQ * TAGS + (size_t)i * TAGS;

#pragma unroll
    for (int k = 0; k < 16; ++k) {
        int f = tid + 64 * k;
        int r = f >> 5, c = f & 31;
        const float4 v = *(const float4*)(src + (size_t)r * SEQ * TAGS + 4 * c);
        uint2 d;
        d.x = pk2u(__expf(v.x) * 0.0625f, __expf(v.y) * 0.0625f);
        d.y = pk2u(__expf(v.z) * 0.0625f, __expf(v.w) * 0.0625f);
        *(uint2*)&ldsT[r * EPITCH + 2 * c] = d;
    }
    __syncthreads();

    const int hi = tid >> 5, n = tid & 31;
    unsigned* dst = gs + ((size_t)blk * 64 + tid) * 32;
    uint2 w[16];
#pragma unroll
    for (int t = 0; t < 4; ++t)
#pragma unroll
        for (int s = 0; s < 4; ++s) {
            int pi = 16 * t + 4 * s + 2 * hi;
            w[t * 4 + s] = *(const uint2*)&ldsT[n * EPITCH + pi];
        }
#pragma unroll
    for (int q = 0; q < 8; ++q)
        ((uint4*)dst)[q] = make_uint4(w[2 * q].x, w[2 * q].y,
                                      w[2 * q + 1].x, w[2 * q + 1].y);
}

// ---------------------------------------------------------------------------
// State pks[32]: dword (ks*4+dw) = f16x2 of rows u=32t+8s+4hi+{2qq,2qq+1},
// ks=2t+(s>>1), dw=2(s&1)+qq. pks[4ks..4ks+3] IS the B-frag for K-slice ks.
// ---------------------------------------------------------------------------
__device__ __forceinline__ void load_g(uint4 (&gq)[8], const unsigned* gs,
                                       int grp, int idx, int lane)
{
    const uint4* p = (const uint4*)(gs + ((size_t)(grp * SEQ + idx) * 64 + lane) * 32);
#pragma unroll
    for (int k = 0; k < 8; ++k) gq[k] = p[k];
}

// One step, in place: pks = f16( (pks.E) * rn ) .* Ghat ;  C += log(q0)+log16
// Split-K dual chains (dep depth 4). q0 from T0 acc row0 (same-step rn —
// stable dead-beat normalization, identical math to r7/r8). shfl+rcp latency
// hidden behind T1-T3 ladder issue.
static __device__ __forceinline__ void step_ft(
    const half8 (&af)[4][8], unsigned (&pks)[32],
    const uint4 (&gq)[8], int hi, float& C)
{
    float16 z{};
    float16 aA[4], aB[4];
#pragma unroll
    for (int T = 0; T < 4; ++T) {
        aA[T] = MFMA(af[T][0], bfrag(pks, 0), z);
        aB[T] = MFMA(af[T][4], bfrag(pks, 4), z);
        aA[T] = MFMA(af[T][1], bfrag(pks, 1), aA[T]);
        aB[T] = MFMA(af[T][5], bfrag(pks, 5), aB[T]);
        aA[T] = MFMA(af[T][2], bfrag(pks, 2), aA[T]);
        aB[T] = MFMA(af[T][6], bfrag(pks, 6), aB[T]);
        aA[T] = MFMA(af[T][3], bfrag(pks, 3), aA[T]);
        aB[T] = MFMA(af[T][7], bfrag(pks, 7), aB[T]);
    }
    float v0 = aA[0][0] + aB[0][0];
    float vp = __shfl_xor(v0, 32, 64);
    float q0 = hi ? vp : v0;
    float rn = __builtin_amdgcn_rcpf(q0);
    C += __logf(q0) + LOG16;
    half2v rnh = __builtin_bit_cast(half2v, pk2u(rn, rn));
    const unsigned* gu = (const unsigned*)gq;
#pragma unroll
    for (int T = 0; T < 4; ++T)
#pragma unroll
        for (int s = 0; s < 4; ++s)
#pragma unroll
            for (int qq = 0; qq < 2; ++qq) {
                int e = 4 * s + 2 * qq;
                half2v hv = __builtin_bit_cast(half2v,
                    pk2u(aA[T][e] + aB[T][e], aA[T][e + 1] + aB[T][e + 1]));
                half2v g2 = __builtin_bit_cast(half2v, gu[(T * 4 + s) * 2 + qq]);
                hv = hv * g2 * rnh;
                pks[(2 * T + (s >> 1)) * 4 + 2 * (s & 1) + qq] =
                    __builtin_bit_cast(unsigned, hv);
            }
}

// bare split-K ladder for the peeled final step
static __device__ __forceinline__ void ladder4(
    const half8 (&af)[4][8], const unsigned (&ps)[32],
    float16 (&oA)[4], float16 (&oB)[4])
{
    float16 z{};
#pragma unroll
    for (int T = 0; T < 4; ++T) {
        oA[T] = MFMA(af[T][0], bfrag(ps, 0), z);
        oB[T] = MFMA(af[T][4], bfrag(ps, 4), z);
        oA[T] = MFMA(af[T][1], bfrag(ps, 1), oA[T]);
        oB[T] = MFMA(af[T][5], bfrag(ps, 5), oB[T]);
        oA[T] = MFMA(af[T][2], bfrag(ps, 2), oA[T]);
        oB[T] = MFMA(af[T][6], bfrag(ps, 6), oB[T]);
        oA[T] = MFMA(af[T][3], bfrag(ps, 3), oA[T]);
        oB[T] = MFMA(af[T][7], bfrag(ps, 7), oB[T]);
    }
}

// ---------------------------------------------------------------------------
// Main kernel: 8 blocks x 1 wave. Blocks 0-3 fwd -> F_512; blocks 4-7 bwd
// -> V = E^T.W_513. Z = F_512 . V per batch col.
// ---------------------------------------------------------------------------
__global__ __launch_bounds__(64, 1)
void crf_seq(const unsigned* __restrict__ gs, const float* __restrict__ Ain,
             float* __restrict__ Fst, float* __restrict__ Vst,
             float* __restrict__ Cf, float* __restrict__ Cb)
{
    const int blk = blockIdx.x;
    const bool fwd = blk < 4;
    const int grp = fwd ? blk : blk - 4;
    const int lane = threadIdx.x;
    const int hi = lane >> 5, l31 = lane & 31;

    // sigma-permuted E A-frags (validated r5-8)
    half8 af[4][8];
#pragma unroll
    for (int T = 0; T < 4; ++T)
#pragma unroll
        for (int ks = 0; ks < 8; ++ks) {
            unsigned q[4];
#pragma unroll
            for (int jj = 0; jj < 4; ++jj) {
                int u0 = 32 * (ks >> 1) + 8 * (2 * (ks & 1) + (jj >> 1))
                       + 4 * hi + 2 * (jj & 1);
                int m = 32 * T + l31;
                float e0, e1;
                if (fwd) { e0 = __expf(Ain[u0 * TAGS + m]);
                           e1 = __expf(Ain[(u0 + 1) * TAGS + m]); }
                else     { e0 = __expf(Ain[m * TAGS + u0]);
                           e1 = __expf(Ain[m * TAGS + u0 + 1]); }
                q[jj] = pk2u(e0, e1);
            }
            uint4 qv = {q[0], q[1], q[2], q[3]};
            af[T][ks] = __builtin_bit_cast(half8, qv);
        }

    // init state from Ghat(start); C = LOG16 accounts the /16 in ghat
    unsigned pks[32];
    {
        const unsigned* g0 = gs + ((size_t)(grp * SEQ + (fwd ? 0 : SEQ - 1)) * 64 + lane) * 32;
#pragma unroll
        for (int t = 0; t < 4; ++t)
#pragma unroll
            for (int s = 0; s < 4; ++s)
#pragma unroll
                for (int qq = 0; qq < 2; ++qq)
                    pks[(2 * t + (s >> 1)) * 4 + 2 * (s & 1) + qq] =
                        g0[(t * 4 + s) * 2 + qq];
    }
    float C = LOG16;
    uint4 gq0[8], gq1[8];
    load_g(gq0, gs, grp, fwd ? 1 : 1022, lane);
    load_g(gq1, gs, grp, fwd ? 2 : 1021, lane);

#pragma unroll 1
    for (int k = 0; k < 255; ++k) {            // 510 steps
        step_ft(af, pks, gq0, hi, C);
        load_g(gq0, gs, grp, fwd ? 2 * k + 3 : 1020 - 2 * k, lane);
        step_ft(af, pks, gq1, hi, C);
        load_g(gq1, gs, grp, fwd ? 2 * k + 4 : 1019 - 2 * k, lane);
    }

    if (fwd) {
        step_ft(af, pks, gq0, hi, C);          // step 511 (G_511)
        // final step 512: bare ladder, write F = acc * rn * ghat_512 (f32)
        float16 oA[4], oB[4];
        ladder4(af, pks, oA, oB);
        float v0 = oA[0][0] + oB[0][0];
        float vp = __shfl_xor(v0, 32, 64);
        float q0 = hi ? vp : v0;
        float rn = __builtin_amdgcn_rcpf(q0);
        C += __logf(q0) + LOG16;               // G_512 is g/16
        const unsigned* gu = (const unsigned*)gq1;  // G_512
        int b = grp * 32 + l31;
#pragma unroll
        for (int T = 0; T < 4; ++T)
#pragma unroll
            for (int s = 0; s < 4; ++s)
#pragma unroll
                for (int qq = 0; qq < 2; ++qq) {
                    half2v g2 = __builtin_bit_cast(half2v, gu[(T * 4 + s) * 2 + qq]);
                    int e = 4 * s + 2 * qq;
                    int u = 32 * T + 8 * s + 4 * hi + 2 * qq;
                    Fst[(size_t)b * TAGS + u] =
                        (oA[T][e] + oB[T][e]) * rn * (float)g2[0];
                    Fst[(size_t)b * TAGS + u + 1] =
                        (oA[T][e + 1] + oB[T][e + 1]) * rn * (float)g2[1];
                }
        if (hi == 0) Cf[b] = C;
    } else {
        // final: V = E^T . W_513, normalized by its own row0
        float16 oA[4], oB[4];
        ladder4(af, pks, oA, oB);
        float v0 = oA[0][0] + oB[0][0];
        float vp = __shfl_xor(v0, 32, 64);
        float q0 = hi ? vp : v0;
        float rn = __builtin_amdgcn_rcpf(q0);
        C += __logf(q0);
        int b = grp * 32 + l31;
#pragma unroll
        for (int T = 0; T < 4; ++T)
#pragma unroll
            for (int r = 0; r < 16; ++r) {
                int u = 32 * T + (r & 3) + 8 * (r >> 2) + 4 * hi;
                Vst[(size_t)b * TAGS + u] = (oA[T][r] + oB[T][r]) * rn;
            }
        if (hi == 0) Cb[b] = C;
    }
}

// logZ_b = Cf + Cb + log(F_512 . V);  out += logZ_b / BATCH
__global__ __launch_bounds__(128, 1)
void crf_combine(const float* __restrict__ Fst, const float* __restrict__ Vst,
                 const float* __restrict__ Cf, const float* __restrict__ Cb,
                 float* __restrict__ out)
{
    int b = threadIdx.x;
    const float* f = Fst + (size_t)b * TAGS;
    const float* v = Vst + (size_t)b * TAGS;
    float s = 0.f;
#pragma unroll
    for (int u = 0; u < TAGS; ++u) s += f[u] * v[u];
    float logZ = Cf[b] + Cb[b] + __logf(s);
    atomicAdd(out, logZ * (1.0f / (float)BATCH));
}

// Gold-path score (validated rounds 1-8): adds -score_b / BATCH
__global__ __launch_bounds__(128, 1)
void crf_score(const float* __restrict__ yp, const int* __restrict__ yt,
               const float* __restrict__ mask, const float* __restrict__ A,
               float* __restrict__ out)
{
    const int b = blockIdx.x;
    const int u = threadIdx.x;
    __shared__ float wred[2];

    const float* __restrict__ ypb = yp + (size_t)b * SEQ * TAGS;
    const float* __restrict__ mb  = mask + (size_t)b * SEQ;
    const int*   __restrict__ ytb = yt + (size_t)b * SEQ;

    float sc = 0.f;
#pragma unroll
    for (int k = 0; k < SEQ / TAGS; ++k) {
        int s = u + k * TAGS;
        int l = ytb[s];
        float m = mb[s];
        sc += ypb[s * TAGS + l] * m;
        if (s + 1 < SEQ) {
            int l2 = ytb[s + 1];
            sc += A[l * TAGS + l2] * m * mb[s + 1];
        }
    }
#pragma unroll
    for (int off = 32; off > 0; off >>= 1)
        sc += __shfl_down(sc, off, 64);
    if ((u & 63) == 0) wred[u >> 6] = sc;
    __syncthreads();
    if (u == 0) atomicAdd(out, -(wred[0] + wred[1]) * (1.0f / (float)BATCH));
}

extern "C" void kernel_launch(void* const* d_in, const int* in_sizes, int n_in,
                              void* d_out, int out_size, void* d_ws, size_t ws_size,
                              hipStream_t stream) {
    const float* yp   = (const float*)d_in[0];   // (128,1024,128) f32
    const int*   yt   = (const int*)d_in[1];     // (128,1024) int
    const float* mask = (const float*)d_in[2];   // (128,1024) f32
    const float* A    = (const float*)d_in[3];   // (128,128) f32
    float* out = (float*)d_out;

    unsigned* gs = (unsigned*)d_ws;
    float* Fst = (float*)((char*)d_ws + GS_BYTES);
    float* Vst = Fst + BATCH * TAGS;
    float* Cf  = Vst + BATCH * TAGS;
    float* Cb  = Cf + BATCH;

    (void)hipMemsetAsync(out, 0, sizeof(float), stream);
    crf_score<<<BATCH, TAGS, 0, stream>>>(yp, yt, mask, A, out);
    exp_pack<<<4 * SEQ, 64, 0, stream>>>(yp, gs);
    crf_seq<<<8, 64, 0, stream>>>(gs, A, Fst, Vst, Cf, Cb);
    crf_combine<<<1, BATCH, 0, stream>>>(Fst, Vst, Cf, Cb, out);
}